// Round 6
// baseline (283.778 us; speedup 1.0000x reference)
//
#include <hip/hip_runtime.h>
#include <cstdint>
#include <cstddef>

#define N_NODES 100000
#define N_EDGES 3200000
#define F_IN 128
#define F_OUT 128
#define KPAD 136   // fallback tiers only

// ---------------- workspace layout ----------------
#define ROWPTR_BYTES ((N_NODES + 1) * 4)
#define O_XB   (((ROWPTR_BYTES) + 255) & ~255)        // 400,128
#define XB_BYTES (N_NODES * F_IN * 2)                 // 25,600,000
#define O_AXB  (O_XB + XB_BYTES)                      // 26,000,128
#define AXB_BYTES (N_NODES * F_OUT * 2)               // 25,600,000
#define O_WT_A (O_AXB + AXB_BYTES)                    // 51,600,128  (Wt directly after AXb:
#define WT_LIN_BYTES (F_OUT * F_IN * 2)               //  gemm overreads <=8KB past AXb -> lands here, allocated)
#define NEED_A ((size_t)(O_WT_A + WT_LIN_BYTES))      // 51,632,896
#define O_WT_A2 O_AXB
#define WT_KPAD_BYTES (F_OUT * KPAD * 2)
#define NEED_A2 ((size_t)(O_WT_A2 + WT_KPAD_BYTES))
#define O_WT_B O_XB
#define NEED_B ((size_t)(O_WT_B + WT_KPAD_BYTES))

typedef __attribute__((ext_vector_type(8))) short short8;   // 8 bf16
typedef __attribute__((ext_vector_type(4))) float f32x4;

// f32 -> bf16 round-to-nearest-even
__device__ __forceinline__ unsigned short f2bf(float f) {
    union { float f; unsigned u; } v; v.f = f;
    return (unsigned short)((v.u + 0x7FFFu + ((v.u >> 16) & 1u)) >> 16);
}
__device__ __forceinline__ float bflo(unsigned u) {
    union { unsigned u; float f; } v; v.u = u << 16; return v.f;
}
__device__ __forceinline__ float bfhi(unsigned u) {
    union { unsigned u; float f; } v; v.u = u & 0xFFFF0000u; return v.f;
}

__device__ __forceinline__ int lower_bound_i32(const int* __restrict__ a, int n, int key) {
    int lo = 0, hi = n;
    while (lo < hi) {
        int mid = (lo + hi) >> 1;
        if (a[mid] < key) lo = mid + 1; else hi = mid;
    }
    return lo;
}

__global__ __launch_bounds__(256) void build_rowptr_kernel(
    const int* __restrict__ rows, int* __restrict__ rowptr)
{
    const int n = blockIdx.x * 256 + threadIdx.x;
    if (n <= N_NODES) rowptr[n] = lower_bound_i32(rows, N_EDGES, n);
}

// x f32 -> xb bf16, fully coalesced: thread i reads float4 x4[i] (16B/lane),
// writes uint2 (8B/lane).
__global__ __launch_bounds__(256) void convert_x_kernel(
    const float4* __restrict__ x4, uint2* __restrict__ xb2)
{
    const unsigned i = blockIdx.x * 256 + threadIdx.x;   // over N*F/4 = 3.2M
    if (i < (N_NODES * F_IN / 4)) {
        const float4 a = x4[i];
        uint2 p;
        p.x = (unsigned)f2bf(a.x) | ((unsigned)f2bf(a.y) << 16);
        p.y = (unsigned)f2bf(a.z) | ((unsigned)f2bf(a.w) << 16);
        xb2[i] = p;
    }
}

// Wt linear bf16: Wt[c][k] = bf16(W[k][c])
__global__ __launch_bounds__(256) void build_wt_lin_kernel(
    const float* __restrict__ W, unsigned short* __restrict__ Wt)
{
    const int idx = blockIdx.x * 256 + threadIdx.x;      // c*128 + k
    if (idx < F_IN * F_OUT) {
        const int c = idx >> 7, k = idx & 127;
        Wt[idx] = f2bf(W[k * F_OUT + c]);
    }
}

// Tier-A2/B Wt: bf16 Wt[c][k], rows padded to KPAD
__global__ __launch_bounds__(256) void build_wt_kpad_kernel(
    const float* __restrict__ W, unsigned short* __restrict__ Wt)
{
    const int idx = blockIdx.x * 256 + threadIdx.x;
    if (idx < F_IN * F_OUT) {
        const int c = idx >> 7, k = idx & 127;
        Wt[c * KPAD + k] = f2bf(W[k * F_OUT + c]);
    }
}

// SpMM over bf16 x: one wave/row, lane owns 2 features, 16-deep gather unroll.
// OUT_MODE 0: f32 float2 -> d_out ; OUT_MODE 1: packed bf16 linear -> AXb(ws)
template<int OUT_MODE>
__global__ __launch_bounds__(256) void spmm_xb_kernel(
    const unsigned* __restrict__ xb,     // [node][64] packed bf16 pairs
    const int*      __restrict__ cols,
    const float*    __restrict__ vals,
    const int*      __restrict__ rowptr,
    void*           __restrict__ outp)
{
    const int row  = blockIdx.x * 4 + (threadIdx.x >> 6);
    const int lane = threadIdx.x & 63;
    if (row >= N_NODES) return;

    const int e0 = rowptr[row], e1 = rowptr[row + 1];
    float ax = 0.f, ay = 0.f;

    int e = e0;
    for (; e + 16 <= e1; e += 16) {
        int c[16]; float v[16]; unsigned u[16];
        #pragma unroll
        for (int j = 0; j < 16; ++j) { c[j] = cols[e + j]; v[j] = vals[e + j]; }
        #pragma unroll
        for (int j = 0; j < 16; ++j) u[j] = xb[(unsigned)c[j] * 64u + lane];
        #pragma unroll
        for (int j = 0; j < 16; ++j) {
            ax = fmaf(v[j], bflo(u[j]), ax);
            ay = fmaf(v[j], bfhi(u[j]), ay);
        }
    }
    for (; e + 4 <= e1; e += 4) {
        int c[4]; float v[4]; unsigned u[4];
        #pragma unroll
        for (int j = 0; j < 4; ++j) { c[j] = cols[e + j]; v[j] = vals[e + j]; }
        #pragma unroll
        for (int j = 0; j < 4; ++j) u[j] = xb[(unsigned)c[j] * 64u + lane];
        #pragma unroll
        for (int j = 0; j < 4; ++j) {
            ax = fmaf(v[j], bflo(u[j]), ax);
            ay = fmaf(v[j], bfhi(u[j]), ay);
        }
    }
    for (; e < e1; ++e) {
        const float v = vals[e];
        const unsigned u = xb[(unsigned)cols[e] * 64u + lane];
        ax = fmaf(v, bflo(u), ax);
        ay = fmaf(v, bfhi(u), ay);
    }

    if (OUT_MODE == 0) {
        float2 o; o.x = ax; o.y = ay;
        reinterpret_cast<float2*>(outp)[(size_t)row * 64 + lane] = o;
    } else {
        const unsigned p = (unsigned)f2bf(ax) | ((unsigned)f2bf(ay) << 16);
        reinterpret_cast<unsigned*>(outp)[(size_t)row * 64 + lane] = p;
    }
}

// LDS-free MFMA GEMM: out[r,:] = relu(AXb[r,:] @ W + b), AXb/Wt linear bf16.
// No LDS, no barrier: fragments loaded straight from global (Wt = 32KB -> L1-hot;
// AXb rows streamed). 4 waves/block, each wave = 16 rows x 128 cols.
// Fragment pattern (verified r4/r5): A row = lane&15, k-chunk = (lane>>4)*8;
// C/D: col = n*16 + (lane&15), row = (lane>>4)*4 + reg.
__global__ __launch_bounds__(256) void gemm_direct_mfma(
    const unsigned short* __restrict__ AXb,
    const unsigned short* __restrict__ Wt,
    const float*          __restrict__ bias,
    float*                __restrict__ out)
{
    const int t    = threadIdx.x;
    const int lane = t & 63;
    const int w    = t >> 6;
    const int lr   = lane & 15;
    const int lg   = lane >> 4;
    const int row0 = blockIdx.x * 64 + w * 16;    // wave's first row

    // A fragments: last block overreads <=8KB past AXb into Wt region (allocated).
    const short* __restrict__ Arow =
        reinterpret_cast<const short*>(AXb) + (size_t)(row0 + lr) * F_IN + lg * 8;
    const short* __restrict__ Wbase =
        reinterpret_cast<const short*>(Wt) + lr * F_IN + lg * 8;

    f32x4 acc[8];
    #pragma unroll
    for (int n = 0; n < 8; ++n) acc[n] = (f32x4){0.f, 0.f, 0.f, 0.f};

    #pragma unroll
    for (int ks = 0; ks < 4; ++ks) {
        const short8 a = *reinterpret_cast<const short8*>(Arow + ks * 32);
        #pragma unroll
        for (int n = 0; n < 8; ++n) {
            const short8 b = *reinterpret_cast<const short8*>(
                Wbase + n * 16 * F_IN + ks * 32);
            acc[n] = __builtin_amdgcn_mfma_f32_16x16x32_bf16(a, b, acc[n], 0, 0, 0);
        }
    }

    const int row_base = row0 + lg * 4;
    #pragma unroll
    for (int n = 0; n < 8; ++n) {
        const int col = n * 16 + lr;
        const float bb = bias[col];
        #pragma unroll
        for (int reg = 0; reg < 4; ++reg) {
            const int r = row_base + reg;
            if (r < N_NODES)
                out[(size_t)r * F_OUT + col] = fmaxf(acc[n][reg] + bb, 0.f);
        }
    }
}

// ---------------- fallback kernels (round-4/5, known-good) ----------------
template<bool USE_ROWPTR>
__global__ __launch_bounds__(256) void spmm_ax_kernel(
    const float* __restrict__ x,
    const int*   __restrict__ rows,
    const int*   __restrict__ cols,
    const float* __restrict__ vals,
    const int*   __restrict__ rowptr,
    float*       __restrict__ out)
{
    const int row  = blockIdx.x * 4 + (threadIdx.x >> 6);
    const int lane = threadIdx.x & 63;
    if (row >= N_NODES) return;
    int e0, e1;
    if (USE_ROWPTR) { e0 = rowptr[row]; e1 = rowptr[row + 1]; }
    else {
        e0 = lower_bound_i32(rows, N_EDGES, row);
        e1 = lower_bound_i32(rows, N_EDGES, row + 1);
    }
    const float2* __restrict__ x2 = reinterpret_cast<const float2*>(x);
    float ax = 0.f, ay = 0.f;
    int e = e0;
    for (; e + 8 <= e1; e += 8) {
        int c[8]; float v[8]; float2 a[8];
        #pragma unroll
        for (int j = 0; j < 8; ++j) { c[j] = cols[e + j]; v[j] = vals[e + j]; }
        #pragma unroll
        for (int j = 0; j < 8; ++j) a[j] = x2[(unsigned)c[j] * 64u + lane];
        #pragma unroll
        for (int j = 0; j < 8; ++j) {
            ax = fmaf(v[j], a[j].x, ax); ay = fmaf(v[j], a[j].y, ay);
        }
    }
    for (; e < e1; ++e) {
        const float v = vals[e];
        const float2 a = x2[(unsigned)cols[e] * 64u + lane];
        ax = fmaf(v, a.x, ax); ay = fmaf(v, a.y, ay);
    }
    float2 o; o.x = ax; o.y = ay;
    reinterpret_cast<float2*>(out)[(size_t)row * 64 + lane] = o;
}

template<bool WT_WS>
__global__ __launch_bounds__(256) void gemm_mfma_bias_relu_inplace(
    float*                __restrict__ out,
    const unsigned short* __restrict__ Wt_ws,
    const float*          __restrict__ W,
    const float*          __restrict__ bias)
{
    __shared__ short A_lds[64][KPAD];
    __shared__ short Wt_lds[F_OUT][KPAD];
    const int t  = threadIdx.x;
    const int r0 = blockIdx.x * 64;
    const int rows_here = (N_NODES - r0 < 64) ? (N_NODES - r0) : 64;
    {
        const float4* __restrict__ A4 =
            reinterpret_cast<const float4*>(out + (size_t)r0 * F_IN);
        const int nA = rows_here * 32;
        for (int i = t; i < nA; i += 256) {
            const int r = i >> 5, q = i & 31;
            const float4 va = A4[i];
            uint2 p;
            p.x = (unsigned)f2bf(va.x) | ((unsigned)f2bf(va.y) << 16);
            p.y = (unsigned)f2bf(va.z) | ((unsigned)f2bf(va.w) << 16);
            *reinterpret_cast<uint2*>(&A_lds[r][q * 4]) = p;
        }
    }
    if (WT_WS) {
        const float4* __restrict__ src = reinterpret_cast<const float4*>(Wt_ws);
        float4* dst = reinterpret_cast<float4*>(&Wt_lds[0][0]);
        for (int i = t; i < (WT_KPAD_BYTES / 16); i += 256) dst[i] = src[i];
    } else {
        if (t < F_OUT)
            for (int k = 0; k < F_IN; ++k)
                Wt_lds[t][k] = (short)f2bf(W[k * F_OUT + t]);
    }
    __syncthreads();

    const int lane = t & 63, w = t >> 6, lr = lane & 15, lg = lane >> 4;
    f32x4 acc[8];
    #pragma unroll
    for (int n = 0; n < 8; ++n) acc[n] = (f32x4){0.f, 0.f, 0.f, 0.f};
    #pragma unroll
    for (int ks = 0; ks < 4; ++ks) {
        const short8 a = *reinterpret_cast<const short8*>(
            &A_lds[w * 16 + lr][ks * 32 + lg * 8]);
        #pragma unroll
        for (int n = 0; n < 8; ++n) {
            const short8 b = *reinterpret_cast<const short8*>(
                &Wt_lds[n * 16 + lr][ks * 32 + lg * 8]);
            acc[n] = __builtin_amdgcn_mfma_f32_16x16x32_bf16(a, b, acc[n], 0, 0, 0);
        }
    }
    const int row_base = r0 + w * 16 + lg * 4;
    #pragma unroll
    for (int n = 0; n < 8; ++n) {
        const int col = n * 16 + lr;
        const float bb = bias[col];
        #pragma unroll
        for (int reg = 0; reg < 4; ++reg) {
            const int r = row_base + reg;
            if (r < N_NODES)
                out[(size_t)r * F_OUT + col] = fmaxf(acc[n][reg] + bb, 0.f);
        }
    }
}

extern "C" void kernel_launch(void* const* d_in, const int* in_sizes, int n_in,
                              void* d_out, int out_size, void* d_ws, size_t ws_size,
                              hipStream_t stream) {
    const float* x    = (const float*)d_in[0];
    const int*   rows = (const int*)  d_in[1];
    const int*   cols = (const int*)  d_in[2];
    const float* vals = (const float*)d_in[3];
    const float* W    = (const float*)d_in[4];
    const float* b    = (const float*)d_in[5];
    float* out = (float*)d_out;
    char*  ws  = (char*)d_ws;

    if (ws_size >= NEED_A) {
        int* rowptr = (int*)ws;
        unsigned short* xb  = (unsigned short*)(ws + O_XB);
        unsigned short* AXb = (unsigned short*)(ws + O_AXB);
        unsigned short* Wt  = (unsigned short*)(ws + O_WT_A);
        build_rowptr_kernel<<<(N_NODES + 256) / 256, 256, 0, stream>>>(rows, rowptr);
        convert_x_kernel<<<(N_NODES * F_IN / 4 + 255) / 256, 256, 0, stream>>>(
            (const float4*)x, (uint2*)xb);
        build_wt_lin_kernel<<<(F_IN * F_OUT + 255) / 256, 256, 0, stream>>>(W, Wt);
        spmm_xb_kernel<1><<<(N_NODES + 3) / 4, 256, 0, stream>>>(
            (const unsigned*)xb, cols, vals, rowptr, AXb);
        gemm_direct_mfma<<<(N_NODES + 63) / 64, 256, 0, stream>>>(AXb, Wt, b, out);
    } else if (ws_size >= NEED_A2) {
        int* rowptr = (int*)ws;
        unsigned short* xb = (unsigned short*)(ws + O_XB);
        unsigned short* Wt = (unsigned short*)(ws + O_WT_A2);
        build_rowptr_kernel<<<(N_NODES + 256) / 256, 256, 0, stream>>>(rows, rowptr);
        convert_x_kernel<<<(N_NODES * F_IN / 4 + 255) / 256, 256, 0, stream>>>(
            (const float4*)x, (uint2*)xb);
        build_wt_kpad_kernel<<<(F_IN * F_OUT + 255) / 256, 256, 0, stream>>>(W, Wt);
        spmm_xb_kernel<0><<<(N_NODES + 3) / 4, 256, 0, stream>>>(
            (const unsigned*)xb, cols, vals, rowptr, out);
        gemm_mfma_bias_relu_inplace<true><<<(N_NODES + 63) / 64, 256, 0, stream>>>(
            out, Wt, nullptr, b);
    } else if (ws_size >= NEED_B) {
        int* rowptr = (int*)ws;
        unsigned short* Wt = (unsigned short*)(ws + O_WT_B);
        build_rowptr_kernel<<<(N_NODES + 256) / 256, 256, 0, stream>>>(rows, rowptr);
        build_wt_kpad_kernel<<<(F_IN * F_OUT + 255) / 256, 256, 0, stream>>>(W, Wt);
        spmm_ax_kernel<true><<<(N_NODES + 3) / 4, 256, 0, stream>>>(
            x, rows, cols, vals, rowptr, out);
        gemm_mfma_bias_relu_inplace<true><<<(N_NODES + 63) / 64, 256, 0, stream>>>(
            out, Wt, nullptr, b);
    } else {
        spmm_ax_kernel<false><<<(N_NODES + 3) / 4, 256, 0, stream>>>(
            x, rows, cols, vals, nullptr, out);
        gemm_mfma_bias_relu_inplace<false><<<(N_NODES + 63) / 64, 256, 0, stream>>>(
            out, nullptr, W, b);
    }
}